// Round 1
// baseline (3881.415 us; speedup 1.0000x reference)
//
#include <hip/hip_runtime.h>
#include <math.h>

#define D 128
#define D4 32   // D/4 float4 chunks per row

// ---------------- K1: edge scatter (gather x_disease row, atomic-add into summed) ----------
__global__ __launch_bounds__(256) void scatter_kernel(
    const float* __restrict__ xd, const int* __restrict__ esrc,
    const int* __restrict__ edst, float* __restrict__ summed,
    float* __restrict__ cnt, int E)
{
    long long gid = (long long)blockIdx.x * blockDim.x + threadIdx.x;
    int e = (int)(gid >> 5);
    int c = (int)(gid & 31);
    if (e >= E) return;
    int s = esrc[e];
    int d = edst[e];
    float4 v = ((const float4*)xd)[s * D4 + c];
    float* o = summed + ((long long)d * D + c * 4);
    unsafeAtomicAdd(o + 0, v.x);
    unsafeAtomicAdd(o + 1, v.y);
    unsafeAtomicAdd(o + 2, v.z);
    unsafeAtomicAdd(o + 3, v.w);
    if (c == 0) unsafeAtomicAdd(cnt + d, 1.0f);
}

// ---------------- K2: h = (summed/max(cnt,1)) @ W_l + b_l + x_gene @ W_r -------------------
// 512 threads: thread = (slot = tid>>5 -> one of 16 rows, j4 = tid&31 -> 4 output cols)
__global__ __launch_bounds__(512) void h_kernel(
    const float* __restrict__ summed, const float* __restrict__ cnt,
    const float* __restrict__ xg, const float* __restrict__ Wl,
    const float* __restrict__ bl, const float* __restrict__ Wr,
    float* __restrict__ hout, int ngene)
{
    __shared__ float4 Wl_s[D * D4];   // 64 KB, row-major [k][j4]
    __shared__ float4 Wr_s[D * D4];   // 64 KB
    __shared__ float  bl_s[D];
    __shared__ __align__(16) float mean_s[16][D];  // 8 KB
    __shared__ __align__(16) float xg_s[16][D];    // 8 KB

    int tid = threadIdx.x;
    for (int i = tid; i < D * D4; i += 512) {
        Wl_s[i] = ((const float4*)Wl)[i];
        Wr_s[i] = ((const float4*)Wr)[i];
    }
    if (tid < D) bl_s[tid] = bl[tid];

    int r = tid >> 5, c = tid & 31;
    int srow = blockIdx.x * 16 + r;
    if (srow < ngene) {
        float inv = 1.0f / fmaxf(cnt[srow], 1.0f);
        float4 sm = ((const float4*)summed)[srow * D4 + c];
        float4 xv = ((const float4*)xg)[srow * D4 + c];
        ((float4*)&mean_s[r][0])[c] = make_float4(sm.x * inv, sm.y * inv, sm.z * inv, sm.w * inv);
        ((float4*)&xg_s[r][0])[c] = xv;
    }
    __syncthreads();

    int j4 = tid & 31, slot = tid >> 5;
    int orow = blockIdx.x * 16 + slot;
    if (orow >= ngene) return;

    float4 acc;
    acc.x = bl_s[4 * j4 + 0];
    acc.y = bl_s[4 * j4 + 1];
    acc.z = bl_s[4 * j4 + 2];
    acc.w = bl_s[4 * j4 + 3];
    #pragma unroll 8
    for (int k = 0; k < D; ++k) {
        float4 wl = Wl_s[k * D4 + j4];
        float4 wr = Wr_s[k * D4 + j4];
        float m = mean_s[slot][k];
        float x = xg_s[slot][k];
        acc.x += m * wl.x + x * wr.x;
        acc.y += m * wl.y + x * wr.y;
        acc.z += m * wl.z + x * wr.z;
        acc.w += m * wl.w + x * wr.w;
    }
    ((float4*)hout)[orow * D4 + j4] = acc;
}

// ---------------- K3: z = h@mu_W+mu_b + eps * exp(h@lv_W+lv_b) (in-place on d_out) ---------
__global__ __launch_bounds__(512) void z_kernel(
    const float* __restrict__ hbuf, const float* __restrict__ eps,
    const float* __restrict__ muW, const float* __restrict__ mub,
    const float* __restrict__ lvW, const float* __restrict__ lvb,
    float* __restrict__ zout, int ngene)
{
    __shared__ float4 muW_s[D * D4];  // 64 KB
    __shared__ float4 lvW_s[D * D4];  // 64 KB
    __shared__ float  mub_s[D];
    __shared__ float  lvb_s[D];
    __shared__ __align__(16) float h_s[16][D];     // 8 KB

    int tid = threadIdx.x;
    for (int i = tid; i < D * D4; i += 512) {
        muW_s[i] = ((const float4*)muW)[i];
        lvW_s[i] = ((const float4*)lvW)[i];
    }
    if (tid < D) { mub_s[tid] = mub[tid]; lvb_s[tid] = lvb[tid]; }

    int r = tid >> 5, c = tid & 31;
    int srow = blockIdx.x * 16 + r;
    if (srow < ngene) {
        ((float4*)&h_s[r][0])[c] = ((const float4*)hbuf)[srow * D4 + c];
    }
    __syncthreads();   // all reads of h rows done before any in-place write

    int j4 = tid & 31, slot = tid >> 5;
    int orow = blockIdx.x * 16 + slot;
    if (orow >= ngene) return;

    float4 amu, alv;
    amu.x = mub_s[4 * j4 + 0]; amu.y = mub_s[4 * j4 + 1];
    amu.z = mub_s[4 * j4 + 2]; amu.w = mub_s[4 * j4 + 3];
    alv.x = lvb_s[4 * j4 + 0]; alv.y = lvb_s[4 * j4 + 1];
    alv.z = lvb_s[4 * j4 + 2]; alv.w = lvb_s[4 * j4 + 3];
    #pragma unroll 8
    for (int k = 0; k < D; ++k) {
        float4 wm = muW_s[k * D4 + j4];
        float4 wv = lvW_s[k * D4 + j4];
        float h = h_s[slot][k];
        amu.x += h * wm.x; amu.y += h * wm.y; amu.z += h * wm.z; amu.w += h * wm.w;
        alv.x += h * wv.x; alv.y += h * wv.y; alv.z += h * wv.z; alv.w += h * wv.w;
    }
    float4 ev = ((const float4*)eps)[orow * D4 + j4];
    float4 z;
    z.x = amu.x + ev.x * expf(alv.x);
    z.y = amu.y + ev.y * expf(alv.y);
    z.z = amu.z + ev.z * expf(alv.z);
    z.w = amu.w + ev.w * expf(alv.w);
    ((float4*)zout)[orow * D4 + j4] = z;
}

extern "C" void kernel_launch(void* const* d_in, const int* in_sizes, int n_in,
                              void* d_out, int out_size, void* d_ws, size_t ws_size,
                              hipStream_t stream)
{
    const float* xd  = (const float*)d_in[0];
    const float* xg  = (const float*)d_in[1];
    const int* esrc  = (const int*)d_in[2];
    const int* edst  = (const int*)d_in[3];
    const float* eps = (const float*)d_in[4];
    const float* Wl  = (const float*)d_in[5];
    const float* bl  = (const float*)d_in[6];
    const float* Wr  = (const float*)d_in[7];
    const float* muW = (const float*)d_in[8];
    const float* mub = (const float*)d_in[9];
    const float* lvW = (const float*)d_in[10];
    const float* lvb = (const float*)d_in[11];

    int E = in_sizes[2];
    int ngene = in_sizes[1] / D;

    float* summed = (float*)d_ws;
    float* cnt = summed + (size_t)ngene * D;

    // zero the accumulators each call (harness does not re-poison between replays)
    hipMemsetAsync(d_ws, 0, ((size_t)ngene * D + (size_t)ngene) * sizeof(float), stream);

    long long total = (long long)E * 32;
    int sblocks = (int)((total + 255) / 256);
    scatter_kernel<<<sblocks, 256, 0, stream>>>(xd, esrc, edst, summed, cnt, E);

    int gblocks = (ngene + 15) / 16;
    float* hbuf = (float*)d_out;   // reuse d_out as h scratch; K3 overwrites in-place
    h_kernel<<<gblocks, 512, 0, stream>>>(summed, cnt, xg, Wl, bl, Wr, hbuf, ngene);
    z_kernel<<<gblocks, 512, 0, stream>>>(hbuf, eps, muW, mub, lvW, lvb, (float*)d_out, ngene);
}

// Round 2
// 828.850 us; speedup vs baseline: 4.6829x; 4.6829x over previous
//
#include <hip/hip_runtime.h>
#include <math.h>

#define D 128
#define D4 32   // D/4 float4 chunks per row
#define CHUNK 1024

// ---------- K_hist: deg[dst]++ over all edges ----------
__global__ __launch_bounds__(256) void hist_kernel(
    const int* __restrict__ edst, int* __restrict__ deg, int E)
{
    for (int e = blockIdx.x * blockDim.x + threadIdx.x; e < E;
         e += gridDim.x * blockDim.x)
        atomicAdd(&deg[edst[e]], 1);
}

// ---------- K_chunksum: chunksum[b] = sum(deg[b*1024 .. +1024)) ----------
__global__ __launch_bounds__(256) void chunksum_kernel(
    const int* __restrict__ deg, int* __restrict__ chunksum, int n)
{
    __shared__ int sc[256];
    int base = blockIdx.x * CHUNK;
    int t = threadIdx.x;
    int s = 0;
    for (int i = t; i < CHUNK; i += 256) {
        int idx = base + i;
        if (idx < n) s += deg[idx];
    }
    sc[t] = s;
    __syncthreads();
    for (int off = 128; off > 0; off >>= 1) {
        if (t < off) sc[t] += sc[t + off];
        __syncthreads();
    }
    if (t == 0) chunksum[blockIdx.x] = sc[0];
}

// ---------- K_scanchunks: exclusive scan of chunksums (single block, <=128 chunks) ----------
__global__ __launch_bounds__(128) void scanchunks_kernel(
    int* __restrict__ chunksum, int* __restrict__ offs, int nchunks, int n, int E)
{
    __shared__ int sc[128];
    int t = threadIdx.x;
    int v = (t < nchunks) ? chunksum[t] : 0;
    sc[t] = v;
    __syncthreads();
    for (int off = 1; off < 128; off <<= 1) {
        int add = (t >= off) ? sc[t - off] : 0;
        __syncthreads();
        sc[t] += add;
        __syncthreads();
    }
    if (t < nchunks) chunksum[t] = sc[t] - v;   // exclusive
    if (t == 0) offs[n] = E;
}

// ---------- K_offsets: offs/cursor from deg + chunk bases ----------
__global__ __launch_bounds__(256) void offsets_kernel(
    const int* __restrict__ deg, const int* __restrict__ chunksum,
    int* __restrict__ offs, int* __restrict__ cursor, int n)
{
    __shared__ int sc[256];
    int base = blockIdx.x * CHUNK;
    int t = threadIdx.x;
    int idx0 = base + t * 4;
    int d0 = 0, d1 = 0, d2 = 0, d3 = 0;
    if (idx0 + 0 < n) d0 = deg[idx0 + 0];
    if (idx0 + 1 < n) d1 = deg[idx0 + 1];
    if (idx0 + 2 < n) d2 = deg[idx0 + 2];
    if (idx0 + 3 < n) d3 = deg[idx0 + 3];
    int mysum = d0 + d1 + d2 + d3;
    sc[t] = mysum;
    __syncthreads();
    for (int off = 1; off < 256; off <<= 1) {
        int add = (t >= off) ? sc[t - off] : 0;
        __syncthreads();
        sc[t] += add;
        __syncthreads();
    }
    int prefix = chunksum[blockIdx.x] + sc[t] - mysum;   // exclusive within chunk
    if (idx0 + 0 < n) { offs[idx0 + 0] = prefix; cursor[idx0 + 0] = prefix; prefix += d0; }
    if (idx0 + 1 < n) { offs[idx0 + 1] = prefix; cursor[idx0 + 1] = prefix; prefix += d1; }
    if (idx0 + 2 < n) { offs[idx0 + 2] = prefix; cursor[idx0 + 2] = prefix; prefix += d2; }
    if (idx0 + 3 < n) { offs[idx0 + 3] = prefix; cursor[idx0 + 3] = prefix; prefix += d3; }
}

// ---------- K_fill: csr_src[pos] = edge_src, bucketed by dst ----------
__global__ __launch_bounds__(256) void fill_kernel(
    const int* __restrict__ esrc, const int* __restrict__ edst,
    int* __restrict__ cursor, int* __restrict__ csr_src, int E)
{
    for (int e = blockIdx.x * blockDim.x + threadIdx.x; e < E;
         e += gridDim.x * blockDim.x) {
        int d = edst[e];
        int pos = atomicAdd(&cursor[d], 1);
        csr_src[pos] = esrc[e];
    }
}

// ---------- K_h fused: gather-mean from CSR + h = mean@W_l + b_l + x_gene@W_r ----------
__global__ __launch_bounds__(512) void h_kernel(
    const int* __restrict__ offs, const int* __restrict__ csr_src,
    const float* __restrict__ xd, const float* __restrict__ xg,
    const float* __restrict__ Wl, const float* __restrict__ bl,
    const float* __restrict__ Wr, float* __restrict__ hout, int ngene)
{
    __shared__ float4 Wl_s[D * D4];   // 64 KB, [k][j4]
    __shared__ float4 Wr_s[D * D4];   // 64 KB
    __shared__ float  bl_s[D];
    __shared__ __align__(16) float mean_s[16][D];  // 8 KB
    __shared__ __align__(16) float xg_s[16][D];    // 8 KB

    int tid = threadIdx.x;
    for (int i = tid; i < D * D4; i += 512) {
        Wl_s[i] = ((const float4*)Wl)[i];
        Wr_s[i] = ((const float4*)Wr)[i];
    }
    if (tid < D) bl_s[tid] = bl[tid];

    int r = tid >> 5, c = tid & 31;
    int srow = blockIdx.x * 16 + r;
    if (srow < ngene) {
        int beg = offs[srow], end = offs[srow + 1];
        const float4* xd4 = (const float4*)xd;
        float4 a0 = make_float4(0.f, 0.f, 0.f, 0.f);
        float4 a1 = make_float4(0.f, 0.f, 0.f, 0.f);
        int i = beg;
        for (; i + 2 <= end; i += 2) {
            int s0 = csr_src[i], s1 = csr_src[i + 1];
            float4 v0 = xd4[s0 * D4 + c];
            float4 v1 = xd4[s1 * D4 + c];
            a0.x += v0.x; a0.y += v0.y; a0.z += v0.z; a0.w += v0.w;
            a1.x += v1.x; a1.y += v1.y; a1.z += v1.z; a1.w += v1.w;
        }
        if (i < end) {
            int s0 = csr_src[i];
            float4 v0 = xd4[s0 * D4 + c];
            a0.x += v0.x; a0.y += v0.y; a0.z += v0.z; a0.w += v0.w;
        }
        float inv = 1.0f / fmaxf((float)(end - beg), 1.0f);
        ((float4*)&mean_s[r][0])[c] = make_float4(
            (a0.x + a1.x) * inv, (a0.y + a1.y) * inv,
            (a0.z + a1.z) * inv, (a0.w + a1.w) * inv);
        ((float4*)&xg_s[r][0])[c] = ((const float4*)xg)[srow * D4 + c];
    }
    __syncthreads();

    int j4 = tid & 31, slot = tid >> 5;
    int orow = blockIdx.x * 16 + slot;
    if (orow >= ngene) return;

    float4 acc;
    acc.x = bl_s[4 * j4 + 0];
    acc.y = bl_s[4 * j4 + 1];
    acc.z = bl_s[4 * j4 + 2];
    acc.w = bl_s[4 * j4 + 3];
    #pragma unroll 8
    for (int k = 0; k < D; ++k) {
        float4 wl = Wl_s[k * D4 + j4];
        float4 wr = Wr_s[k * D4 + j4];
        float m = mean_s[slot][k];
        float x = xg_s[slot][k];
        acc.x += m * wl.x + x * wr.x;
        acc.y += m * wl.y + x * wr.y;
        acc.z += m * wl.z + x * wr.z;
        acc.w += m * wl.w + x * wr.w;
    }
    ((float4*)hout)[orow * D4 + j4] = acc;
}

// ---------- K_z: z = h@mu_W+mu_b + eps * exp(h@lv_W+lv_b) (in-place on d_out) ----------
__global__ __launch_bounds__(512) void z_kernel(
    const float* __restrict__ hbuf, const float* __restrict__ eps,
    const float* __restrict__ muW, const float* __restrict__ mub,
    const float* __restrict__ lvW, const float* __restrict__ lvb,
    float* __restrict__ zout, int ngene)
{
    __shared__ float4 muW_s[D * D4];  // 64 KB
    __shared__ float4 lvW_s[D * D4];  // 64 KB
    __shared__ float  mub_s[D];
    __shared__ float  lvb_s[D];
    __shared__ __align__(16) float h_s[16][D];     // 8 KB

    int tid = threadIdx.x;
    for (int i = tid; i < D * D4; i += 512) {
        muW_s[i] = ((const float4*)muW)[i];
        lvW_s[i] = ((const float4*)lvW)[i];
    }
    if (tid < D) { mub_s[tid] = mub[tid]; lvb_s[tid] = lvb[tid]; }

    int r = tid >> 5, c = tid & 31;
    int srow = blockIdx.x * 16 + r;
    if (srow < ngene) {
        ((float4*)&h_s[r][0])[c] = ((const float4*)hbuf)[srow * D4 + c];
    }
    __syncthreads();

    int j4 = tid & 31, slot = tid >> 5;
    int orow = blockIdx.x * 16 + slot;
    if (orow >= ngene) return;

    float4 amu, alv;
    amu.x = mub_s[4 * j4 + 0]; amu.y = mub_s[4 * j4 + 1];
    amu.z = mub_s[4 * j4 + 2]; amu.w = mub_s[4 * j4 + 3];
    alv.x = lvb_s[4 * j4 + 0]; alv.y = lvb_s[4 * j4 + 1];
    alv.z = lvb_s[4 * j4 + 2]; alv.w = lvb_s[4 * j4 + 3];
    #pragma unroll 8
    for (int k = 0; k < D; ++k) {
        float4 wm = muW_s[k * D4 + j4];
        float4 wv = lvW_s[k * D4 + j4];
        float h = h_s[slot][k];
        amu.x += h * wm.x; amu.y += h * wm.y; amu.z += h * wm.z; amu.w += h * wm.w;
        alv.x += h * wv.x; alv.y += h * wv.y; alv.z += h * wv.z; alv.w += h * wv.w;
    }
    float4 ev = ((const float4*)eps)[orow * D4 + j4];
    float4 z;
    z.x = amu.x + ev.x * expf(alv.x);
    z.y = amu.y + ev.y * expf(alv.y);
    z.z = amu.z + ev.z * expf(alv.z);
    z.w = amu.w + ev.w * expf(alv.w);
    ((float4*)zout)[orow * D4 + j4] = z;
}

extern "C" void kernel_launch(void* const* d_in, const int* in_sizes, int n_in,
                              void* d_out, int out_size, void* d_ws, size_t ws_size,
                              hipStream_t stream)
{
    const float* xd  = (const float*)d_in[0];
    const float* xg  = (const float*)d_in[1];
    const int* esrc  = (const int*)d_in[2];
    const int* edst  = (const int*)d_in[3];
    const float* eps = (const float*)d_in[4];
    const float* Wl  = (const float*)d_in[5];
    const float* bl  = (const float*)d_in[6];
    const float* Wr  = (const float*)d_in[7];
    const float* muW = (const float*)d_in[8];
    const float* mub = (const float*)d_in[9];
    const float* lvW = (const float*)d_in[10];
    const float* lvb = (const float*)d_in[11];

    int E = in_sizes[2];
    int ngene = in_sizes[1] / D;
    int nchunks = (ngene + CHUNK - 1) / CHUNK;   // 98 for ngene=100000 (<=128 required)

    // ws layout (ints)
    int* deg      = (int*)d_ws;                  // [ngene]
    int* offs     = deg + ngene;                 // [ngene+1]
    int* cursor   = offs + ngene + 1;            // [ngene]
    int* chunksum = cursor + ngene;              // [128]
    int* csr_src  = chunksum + 128;              // [E]

    hipMemsetAsync(deg, 0, (size_t)ngene * sizeof(int), stream);

    hist_kernel<<<2048, 256, 0, stream>>>(edst, deg, E);
    chunksum_kernel<<<nchunks, 256, 0, stream>>>(deg, chunksum, ngene);
    scanchunks_kernel<<<1, 128, 0, stream>>>(chunksum, offs, nchunks, ngene, E);
    offsets_kernel<<<nchunks, 256, 0, stream>>>(deg, chunksum, offs, cursor, ngene);
    fill_kernel<<<2048, 256, 0, stream>>>(esrc, edst, cursor, csr_src, E);

    int gblocks = (ngene + 15) / 16;
    float* hbuf = (float*)d_out;   // reuse d_out as h scratch; z overwrites in-place
    h_kernel<<<gblocks, 512, 0, stream>>>(offs, csr_src, xd, xg, Wl, bl, Wr, hbuf, ngene);
    z_kernel<<<gblocks, 512, 0, stream>>>(hbuf, eps, muW, mub, lvW, lvb, (float*)d_out, ngene);
}

// Round 3
// 409.684 us; speedup vs baseline: 9.4742x; 2.0231x over previous
//
#include <hip/hip_runtime.h>
#include <math.h>

#define D 128
#define CHUNK 1024

typedef short bf16x8 __attribute__((ext_vector_type(8)));
typedef float f32x4 __attribute__((ext_vector_type(4)));

__device__ inline unsigned short f2bf(float f) {
    union { float f; unsigned u; } v; v.f = f;
    unsigned r = v.u + 0x7fff + ((v.u >> 16) & 1);   // RNE
    return (unsigned short)(r >> 16);
}
__device__ inline float bf2f(unsigned short u) {
    union { unsigned u; float f; } v; v.u = ((unsigned)u) << 16;
    return v.f;
}

// ---------- CSR build ----------
__global__ __launch_bounds__(256) void hist_kernel(
    const int* __restrict__ edst, int* __restrict__ deg, int E)
{
    for (int e = blockIdx.x * blockDim.x + threadIdx.x; e < E;
         e += gridDim.x * blockDim.x)
        atomicAdd(&deg[edst[e]], 1);
}

__global__ __launch_bounds__(256) void chunksum_kernel(
    const int* __restrict__ deg, int* __restrict__ chunksum, int n)
{
    __shared__ int sc[256];
    int base = blockIdx.x * CHUNK;
    int t = threadIdx.x;
    int s = 0;
    for (int i = t; i < CHUNK; i += 256) {
        int idx = base + i;
        if (idx < n) s += deg[idx];
    }
    sc[t] = s;
    __syncthreads();
    for (int off = 128; off > 0; off >>= 1) {
        if (t < off) sc[t] += sc[t + off];
        __syncthreads();
    }
    if (t == 0) chunksum[blockIdx.x] = sc[0];
}

__global__ __launch_bounds__(128) void scanchunks_kernel(
    int* __restrict__ chunksum, int* __restrict__ offs, int nchunks, int n, int E)
{
    __shared__ int sc[128];
    int t = threadIdx.x;
    int v = (t < nchunks) ? chunksum[t] : 0;
    sc[t] = v;
    __syncthreads();
    for (int off = 1; off < 128; off <<= 1) {
        int add = (t >= off) ? sc[t - off] : 0;
        __syncthreads();
        sc[t] += add;
        __syncthreads();
    }
    if (t < nchunks) chunksum[t] = sc[t] - v;   // exclusive
    if (t == 0) offs[n] = E;
}

__global__ __launch_bounds__(256) void offsets_kernel(
    const int* __restrict__ deg, const int* __restrict__ chunksum,
    int* __restrict__ offs, int* __restrict__ cursor, int n)
{
    __shared__ int sc[256];
    int base = blockIdx.x * CHUNK;
    int t = threadIdx.x;
    int idx0 = base + t * 4;
    int d0 = 0, d1 = 0, d2 = 0, d3 = 0;
    if (idx0 + 0 < n) d0 = deg[idx0 + 0];
    if (idx0 + 1 < n) d1 = deg[idx0 + 1];
    if (idx0 + 2 < n) d2 = deg[idx0 + 2];
    if (idx0 + 3 < n) d3 = deg[idx0 + 3];
    int mysum = d0 + d1 + d2 + d3;
    sc[t] = mysum;
    __syncthreads();
    for (int off = 1; off < 256; off <<= 1) {
        int add = (t >= off) ? sc[t - off] : 0;
        __syncthreads();
        sc[t] += add;
        __syncthreads();
    }
    int prefix = chunksum[blockIdx.x] + sc[t] - mysum;
    if (idx0 + 0 < n) { offs[idx0 + 0] = prefix; cursor[idx0 + 0] = prefix; prefix += d0; }
    if (idx0 + 1 < n) { offs[idx0 + 1] = prefix; cursor[idx0 + 1] = prefix; prefix += d1; }
    if (idx0 + 2 < n) { offs[idx0 + 2] = prefix; cursor[idx0 + 2] = prefix; prefix += d2; }
    if (idx0 + 3 < n) { offs[idx0 + 3] = prefix; cursor[idx0 + 3] = prefix; prefix += d3; }
}

__global__ __launch_bounds__(256) void fill_kernel(
    const int* __restrict__ esrc, const int* __restrict__ edst,
    int* __restrict__ cursor, int* __restrict__ csr_src, int E)
{
    for (int e = blockIdx.x * blockDim.x + threadIdx.x; e < E;
         e += gridDim.x * blockDim.x) {
        int d = edst[e];
        int pos = atomicAdd(&cursor[d], 1);
        csr_src[pos] = esrc[e];
    }
}

// ---------- conversions ----------
__global__ __launch_bounds__(256) void cvt_xd_kernel(
    const float* __restrict__ src, unsigned short* __restrict__ dst, int n8)
{
    int i = blockIdx.x * blockDim.x + threadIdx.x;
    if (i >= n8) return;
    float4 a = ((const float4*)src)[i * 2];
    float4 b = ((const float4*)src)[i * 2 + 1];
    bf16x8 v;
    v[0] = (short)f2bf(a.x); v[1] = (short)f2bf(a.y);
    v[2] = (short)f2bf(a.z); v[3] = (short)f2bf(a.w);
    v[4] = (short)f2bf(b.x); v[5] = (short)f2bf(b.y);
    v[6] = (short)f2bf(b.z); v[7] = (short)f2bf(b.w);
    ((bf16x8*)dst)[i] = v;
}

// transpose 128x128 f32 -> bf16 (WT[n][k] = W[k][n]); blockIdx picks matrix
__global__ __launch_bounds__(256) void cvt_w_kernel(
    const float* __restrict__ w0, const float* __restrict__ w1,
    const float* __restrict__ w2, const float* __restrict__ w3,
    unsigned short* __restrict__ t0, unsigned short* __restrict__ t1,
    unsigned short* __restrict__ t2, unsigned short* __restrict__ t3)
{
    const float* src = blockIdx.x == 0 ? w0 : blockIdx.x == 1 ? w1
                     : blockIdx.x == 2 ? w2 : w3;
    unsigned short* dst = blockIdx.x == 0 ? t0 : blockIdx.x == 1 ? t1
                        : blockIdx.x == 2 ? t2 : t3;
    for (int idx = threadIdx.x; idx < D * D; idx += 256) {
        int k = idx >> 7, n = idx & 127;
        dst[n * D + k] = f2bf(src[idx]);
    }
}

// ---------- gather: mean_bf16[row] = mean over neighbors of xd_bf16 ----------
__global__ __launch_bounds__(256, 6) void gather_kernel(
    const int* __restrict__ offs, const int* __restrict__ csr,
    const unsigned short* __restrict__ xdb, unsigned short* __restrict__ meanb,
    int ngene)
{
    int tid = threadIdx.x;
    int r = tid >> 4, c = tid & 15;
    int row = blockIdx.x * 16 + r;
    if (row >= ngene) return;
    int beg = offs[row], end = offs[row + 1];
    const bf16x8* tab = (const bf16x8*)xdb;
    float a0[8] = {0, 0, 0, 0, 0, 0, 0, 0};
    float a1[8] = {0, 0, 0, 0, 0, 0, 0, 0};
    int i = beg;
    for (; i + 2 <= end; i += 2) {
        int s0 = csr[i], s1 = csr[i + 1];
        bf16x8 v0 = tab[s0 * 16 + c];
        bf16x8 v1 = tab[s1 * 16 + c];
        #pragma unroll
        for (int j = 0; j < 8; ++j) {
            a0[j] += bf2f((unsigned short)v0[j]);
            a1[j] += bf2f((unsigned short)v1[j]);
        }
    }
    if (i < end) {
        int s0 = csr[i];
        bf16x8 v0 = tab[s0 * 16 + c];
        #pragma unroll
        for (int j = 0; j < 8; ++j) a0[j] += bf2f((unsigned short)v0[j]);
    }
    float inv = 1.0f / fmaxf((float)(end - beg), 1.0f);
    bf16x8 o;
    #pragma unroll
    for (int j = 0; j < 8; ++j) o[j] = (short)f2bf((a0[j] + a1[j]) * inv);
    ((bf16x8*)meanb)[row * 16 + c] = o;
}

// ---------- fused h+z MFMA kernel ----------
// block = 256 thr = 4 waves; wave w owns cols [32w,32w+32) as two 16x16 tiles.
// A-frag layout (16x16x32 bf16): row=lane&15, k=(lane>>4)*8+j
// B-frag layout:                 col=lane&15, k=(lane>>4)*8+j  (load from W^T)
// C/D layout:                    col=lane&15, row=(lane>>4)*4+reg
__global__ __launch_bounds__(256, 2) void hz_kernel(
    const unsigned short* __restrict__ meanb, const float* __restrict__ xg,
    const float* __restrict__ eps,
    const unsigned short* __restrict__ WlT, const unsigned short* __restrict__ WrT,
    const unsigned short* __restrict__ muT, const unsigned short* __restrict__ lvT,
    const float* __restrict__ bl, const float* __restrict__ mub,
    const float* __restrict__ lvb, float* __restrict__ z, int ntiles)
{
    __shared__ unsigned short h_s[16][136];   // +8 pad

    int tid = threadIdx.x;
    int wave = tid >> 6;
    int lane = tid & 63;
    int lr = lane & 15;
    int lg = lane >> 4;

    int cb0 = wave * 32;
    int cb1 = cb0 + 16;

    bf16x8 wl[2][4], wr[2][4], mu[2][4], lv[2][4];
    #pragma unroll
    for (int kc = 0; kc < 4; ++kc) {
        int koff = kc * 32 + lg * 8;
        wl[0][kc] = *(const bf16x8*)&WlT[(cb0 + lr) * D + koff];
        wl[1][kc] = *(const bf16x8*)&WlT[(cb1 + lr) * D + koff];
        wr[0][kc] = *(const bf16x8*)&WrT[(cb0 + lr) * D + koff];
        wr[1][kc] = *(const bf16x8*)&WrT[(cb1 + lr) * D + koff];
        mu[0][kc] = *(const bf16x8*)&muT[(cb0 + lr) * D + koff];
        mu[1][kc] = *(const bf16x8*)&muT[(cb1 + lr) * D + koff];
        lv[0][kc] = *(const bf16x8*)&lvT[(cb0 + lr) * D + koff];
        lv[1][kc] = *(const bf16x8*)&lvT[(cb1 + lr) * D + koff];
    }
    float bias0 = bl[cb0 + lr], bias1 = bl[cb1 + lr];
    float mb0 = mub[cb0 + lr], mb1 = mub[cb1 + lr];
    float lb0 = lvb[cb0 + lr], lb1 = lvb[cb1 + lr];

    for (int t = blockIdx.x; t < ntiles; t += gridDim.x) {
        int rowbase = t * 16;
        int arow = rowbase + lr;

        bf16x8 am[4], ax[4];
        #pragma unroll
        for (int kc = 0; kc < 4; ++kc) {
            int koff = kc * 32 + lg * 8;
            am[kc] = *(const bf16x8*)&meanb[arow * D + koff];
            const float* xp = &xg[arow * D + koff];
            float4 x0 = *(const float4*)xp;
            float4 x1 = *(const float4*)(xp + 4);
            bf16x8 v;
            v[0] = (short)f2bf(x0.x); v[1] = (short)f2bf(x0.y);
            v[2] = (short)f2bf(x0.z); v[3] = (short)f2bf(x0.w);
            v[4] = (short)f2bf(x1.x); v[5] = (short)f2bf(x1.y);
            v[6] = (short)f2bf(x1.z); v[7] = (short)f2bf(x1.w);
            ax[kc] = v;
        }

        f32x4 h0 = {bias0, bias0, bias0, bias0};
        f32x4 h1 = {bias1, bias1, bias1, bias1};
        #pragma unroll
        for (int kc = 0; kc < 4; ++kc) {
            h0 = __builtin_amdgcn_mfma_f32_16x16x32_bf16(am[kc], wl[0][kc], h0, 0, 0, 0);
            h1 = __builtin_amdgcn_mfma_f32_16x16x32_bf16(am[kc], wl[1][kc], h1, 0, 0, 0);
            h0 = __builtin_amdgcn_mfma_f32_16x16x32_bf16(ax[kc], wr[0][kc], h0, 0, 0, 0);
            h1 = __builtin_amdgcn_mfma_f32_16x16x32_bf16(ax[kc], wr[1][kc], h1, 0, 0, 0);
        }

        __syncthreads();   // prev iteration's z-phase LDS reads complete
        #pragma unroll
        for (int r = 0; r < 4; ++r) {
            int rit = lg * 4 + r;
            h_s[rit][cb0 + lr] = f2bf(h0[r]);
            h_s[rit][cb1 + lr] = f2bf(h1[r]);
        }
        __syncthreads();

        bf16x8 ah[4];
        #pragma unroll
        for (int kc = 0; kc < 4; ++kc) {
            int koff = kc * 32 + lg * 8;
            ah[kc] = *(const bf16x8*)&h_s[lr][koff];
        }
        f32x4 zm0 = {mb0, mb0, mb0, mb0}, zm1 = {mb1, mb1, mb1, mb1};
        f32x4 zl0 = {lb0, lb0, lb0, lb0}, zl1 = {lb1, lb1, lb1, lb1};
        #pragma unroll
        for (int kc = 0; kc < 4; ++kc) {
            zm0 = __builtin_amdgcn_mfma_f32_16x16x32_bf16(ah[kc], mu[0][kc], zm0, 0, 0, 0);
            zm1 = __builtin_amdgcn_mfma_f32_16x16x32_bf16(ah[kc], mu[1][kc], zm1, 0, 0, 0);
            zl0 = __builtin_amdgcn_mfma_f32_16x16x32_bf16(ah[kc], lv[0][kc], zl0, 0, 0, 0);
            zl1 = __builtin_amdgcn_mfma_f32_16x16x32_bf16(ah[kc], lv[1][kc], zl1, 0, 0, 0);
        }
        #pragma unroll
        for (int r = 0; r < 4; ++r) {
            int orow = rowbase + lg * 4 + r;
            float e0 = eps[orow * D + cb0 + lr];
            float e1 = eps[orow * D + cb1 + lr];
            z[orow * D + cb0 + lr] = zm0[r] + e0 * __expf(zl0[r]);
            z[orow * D + cb1 + lr] = zm1[r] + e1 * __expf(zl1[r]);
        }
    }
}

extern "C" void kernel_launch(void* const* d_in, const int* in_sizes, int n_in,
                              void* d_out, int out_size, void* d_ws, size_t ws_size,
                              hipStream_t stream)
{
    const float* xd  = (const float*)d_in[0];
    const float* xg  = (const float*)d_in[1];
    const int* esrc  = (const int*)d_in[2];
    const int* edst  = (const int*)d_in[3];
    const float* eps = (const float*)d_in[4];
    const float* Wl  = (const float*)d_in[5];
    const float* bl  = (const float*)d_in[6];
    const float* Wr  = (const float*)d_in[7];
    const float* muW = (const float*)d_in[8];
    const float* mub = (const float*)d_in[9];
    const float* lvW = (const float*)d_in[10];
    const float* lvb = (const float*)d_in[11];

    int E = in_sizes[2];
    int ndis = in_sizes[0] / D;      // 20000
    int ngene = in_sizes[1] / D;     // 100000
    int nchunks = (ngene + CHUNK - 1) / CHUNK;   // 98 (<=128)

    // ---- ws layout ----
    char* p = (char*)d_ws;
    int* deg      = (int*)p;  p += (size_t)ngene * 4;
    int* offs     = (int*)p;  p += (size_t)(ngene + 1) * 4;
    int* cursor   = (int*)p;  p += (size_t)ngene * 4;
    int* chunksum = (int*)p;  p += 128 * 4;
    p = (char*)(((size_t)p + 255) & ~(size_t)255);
    unsigned short* xdb   = (unsigned short*)p;  p += (size_t)ndis * D * 2;
    unsigned short* WlT   = (unsigned short*)p;  p += D * D * 2;
    unsigned short* WrT   = (unsigned short*)p;  p += D * D * 2;
    unsigned short* muT   = (unsigned short*)p;  p += D * D * 2;
    unsigned short* lvT   = (unsigned short*)p;  p += D * D * 2;
    unsigned short* meanb = (unsigned short*)p;  p += (size_t)ngene * D * 2;
    int* csr_src  = (int*)p;  // E ints

    hipMemsetAsync(deg, 0, (size_t)ngene * sizeof(int), stream);

    hist_kernel<<<2048, 256, 0, stream>>>(edst, deg, E);
    chunksum_kernel<<<nchunks, 256, 0, stream>>>(deg, chunksum, ngene);
    scanchunks_kernel<<<1, 128, 0, stream>>>(chunksum, offs, nchunks, ngene, E);
    offsets_kernel<<<nchunks, 256, 0, stream>>>(deg, chunksum, offs, cursor, ngene);
    fill_kernel<<<2048, 256, 0, stream>>>(esrc, edst, cursor, csr_src, E);

    int n8 = ndis * D / 8;
    cvt_xd_kernel<<<(n8 + 255) / 256, 256, 0, stream>>>(xd, xdb, n8);
    cvt_w_kernel<<<4, 256, 0, stream>>>(Wl, Wr, muW, lvW, WlT, WrT, muT, lvT);

    gather_kernel<<<(ngene + 15) / 16, 256, 0, stream>>>(offs, csr_src, xdb, meanb, ngene);

    int ntiles = (ngene + 15) / 16;   // 6250 (exact for 100000)
    hz_kernel<<<2048, 256, 0, stream>>>(meanb, xg, eps, WlT, WrT, muT, lvT,
                                        bl, mub, lvb, (float*)d_out, ntiles);
}

// Round 4
// 326.696 us; speedup vs baseline: 11.8808x; 1.2540x over previous
//
#include <hip/hip_runtime.h>
#include <math.h>

#define D 128
#define CHUNK 1024
#define NPART 8   // dst-range partitions == XCD count; blockIdx%8 -> XCD round-robin

typedef short bf16x8 __attribute__((ext_vector_type(8)));
typedef float f32x4 __attribute__((ext_vector_type(4)));

__device__ inline unsigned short f2bf(float f) {
    union { float f; unsigned u; } v; v.f = f;
    unsigned r = v.u + 0x7fff + ((v.u >> 16) & 1);   // RNE
    return (unsigned short)(r >> 16);
}
__device__ inline float bf2f(unsigned short u) {
    union { unsigned u; float f; } v; v.u = ((unsigned)u) << 16;
    return v.f;
}

// ---------- CSR build ----------
__global__ __launch_bounds__(256) void hist_kernel(
    const int* __restrict__ edst, int* __restrict__ deg, int E)
{
    for (int e = blockIdx.x * blockDim.x + threadIdx.x; e < E;
         e += gridDim.x * blockDim.x)
        atomicAdd(&deg[edst[e]], 1);
}

__global__ __launch_bounds__(256) void chunksum_kernel(
    const int* __restrict__ deg, int* __restrict__ chunksum, int n)
{
    __shared__ int sc[256];
    int base = blockIdx.x * CHUNK;
    int t = threadIdx.x;
    int s = 0;
    for (int i = t; i < CHUNK; i += 256) {
        int idx = base + i;
        if (idx < n) s += deg[idx];
    }
    sc[t] = s;
    __syncthreads();
    for (int off = 128; off > 0; off >>= 1) {
        if (t < off) sc[t] += sc[t + off];
        __syncthreads();
    }
    if (t == 0) chunksum[blockIdx.x] = sc[0];
}

__global__ __launch_bounds__(128) void scanchunks_kernel(
    int* __restrict__ chunksum, int* __restrict__ offs, int nchunks, int n, int E)
{
    __shared__ int sc[128];
    int t = threadIdx.x;
    int v = (t < nchunks) ? chunksum[t] : 0;
    sc[t] = v;
    __syncthreads();
    for (int off = 1; off < 128; off <<= 1) {
        int add = (t >= off) ? sc[t - off] : 0;
        __syncthreads();
        sc[t] += add;
        __syncthreads();
    }
    if (t < nchunks) chunksum[t] = sc[t] - v;   // exclusive
    if (t == 0) offs[n] = E;
}

__global__ __launch_bounds__(256) void offsets_kernel(
    const int* __restrict__ deg, const int* __restrict__ chunksum,
    int* __restrict__ offs, int* __restrict__ cursor, int n)
{
    __shared__ int sc[256];
    int base = blockIdx.x * CHUNK;
    int t = threadIdx.x;
    int idx0 = base + t * 4;
    int d0 = 0, d1 = 0, d2 = 0, d3 = 0;
    if (idx0 + 0 < n) d0 = deg[idx0 + 0];
    if (idx0 + 1 < n) d1 = deg[idx0 + 1];
    if (idx0 + 2 < n) d2 = deg[idx0 + 2];
    if (idx0 + 3 < n) d3 = deg[idx0 + 3];
    int mysum = d0 + d1 + d2 + d3;
    sc[t] = mysum;
    __syncthreads();
    for (int off = 1; off < 256; off <<= 1) {
        int add = (t >= off) ? sc[t - off] : 0;
        __syncthreads();
        sc[t] += add;
        __syncthreads();
    }
    int prefix = chunksum[blockIdx.x] + sc[t] - mysum;
    if (idx0 + 0 < n) { offs[idx0 + 0] = prefix; cursor[idx0 + 0] = prefix; prefix += d0; }
    if (idx0 + 1 < n) { offs[idx0 + 1] = prefix; cursor[idx0 + 1] = prefix; prefix += d1; }
    if (idx0 + 2 < n) { offs[idx0 + 2] = prefix; cursor[idx0 + 2] = prefix; prefix += d2; }
    if (idx0 + 3 < n) { offs[idx0 + 3] = prefix; cursor[idx0 + 3] = prefix; prefix += d3; }
}

// ---------- K_fill: dst-partitioned scatter; partition p's csr region stays in XCD p's L2 ----
__global__ __launch_bounds__(256) void fill_kernel(
    const int* __restrict__ esrc, const int* __restrict__ edst,
    int* __restrict__ cursor, int* __restrict__ csr_src, int E, int ngene)
{
    int part = blockIdx.x & (NPART - 1);
    int slice = blockIdx.x >> 3;
    int nslices = gridDim.x >> 3;
    int lo = (int)((long long)part * ngene / NPART);
    int hi = (int)((long long)(part + 1) * ngene / NPART);
    int e0 = (int)((long long)slice * E / nslices);
    int e1 = (int)((long long)(slice + 1) * E / nslices);
    for (int e = e0 + threadIdx.x; e < e1; e += 256) {
        int d = edst[e];
        if (d >= lo && d < hi) {
            int pos = atomicAdd(&cursor[d], 1);
            csr_src[pos] = esrc[e];
        }
    }
}

// ---------- conversions ----------
__global__ __launch_bounds__(256) void cvt_xd_kernel(
    const float* __restrict__ src, unsigned short* __restrict__ dst, int n8)
{
    int i = blockIdx.x * blockDim.x + threadIdx.x;
    if (i >= n8) return;
    float4 a = ((const float4*)src)[i * 2];
    float4 b = ((const float4*)src)[i * 2 + 1];
    bf16x8 v;
    v[0] = (short)f2bf(a.x); v[1] = (short)f2bf(a.y);
    v[2] = (short)f2bf(a.z); v[3] = (short)f2bf(a.w);
    v[4] = (short)f2bf(b.x); v[5] = (short)f2bf(b.y);
    v[6] = (short)f2bf(b.z); v[7] = (short)f2bf(b.w);
    ((bf16x8*)dst)[i] = v;
}

// transpose 128x128 f32 -> bf16 (WT[n][k] = W[k][n]); blockIdx picks matrix
__global__ __launch_bounds__(256) void cvt_w_kernel(
    const float* __restrict__ w0, const float* __restrict__ w1,
    const float* __restrict__ w2, const float* __restrict__ w3,
    unsigned short* __restrict__ t0, unsigned short* __restrict__ t1,
    unsigned short* __restrict__ t2, unsigned short* __restrict__ t3)
{
    const float* src = blockIdx.x == 0 ? w0 : blockIdx.x == 1 ? w1
                     : blockIdx.x == 2 ? w2 : w3;
    unsigned short* dst = blockIdx.x == 0 ? t0 : blockIdx.x == 1 ? t1
                        : blockIdx.x == 2 ? t2 : t3;
    for (int idx = threadIdx.x; idx < D * D; idx += 256) {
        int k = idx >> 7, n = idx & 127;
        dst[n * D + k] = f2bf(src[idx]);
    }
}

// ---------- gather: mean_bf16[row] = mean over neighbors of xd_bf16 ----------
__global__ __launch_bounds__(256, 6) void gather_kernel(
    const int* __restrict__ offs, const int* __restrict__ csr,
    const unsigned short* __restrict__ xdb, unsigned short* __restrict__ meanb,
    int ngene)
{
    int tid = threadIdx.x;
    int r = tid >> 4, c = tid & 15;
    int row = blockIdx.x * 16 + r;
    if (row >= ngene) return;
    int beg = offs[row], end = offs[row + 1];
    const bf16x8* tab = (const bf16x8*)xdb;
    float a0[8] = {0, 0, 0, 0, 0, 0, 0, 0};
    float a1[8] = {0, 0, 0, 0, 0, 0, 0, 0};
    int i = beg;
    for (; i + 2 <= end; i += 2) {
        int s0 = csr[i], s1 = csr[i + 1];
        bf16x8 v0 = tab[s0 * 16 + c];
        bf16x8 v1 = tab[s1 * 16 + c];
        #pragma unroll
        for (int j = 0; j < 8; ++j) {
            a0[j] += bf2f((unsigned short)v0[j]);
            a1[j] += bf2f((unsigned short)v1[j]);
        }
    }
    if (i < end) {
        int s0 = csr[i];
        bf16x8 v0 = tab[s0 * 16 + c];
        #pragma unroll
        for (int j = 0; j < 8; ++j) a0[j] += bf2f((unsigned short)v0[j]);
    }
    float inv = 1.0f / fmaxf((float)(end - beg), 1.0f);
    bf16x8 o;
    #pragma unroll
    for (int j = 0; j < 8; ++j) o[j] = (short)f2bf((a0[j] + a1[j]) * inv);
    ((bf16x8*)meanb)[row * 16 + c] = o;
}

// ---------- fused h+z MFMA kernel ----------
// block = 256 thr = 4 waves; wave w owns cols [32w,32w+32) as two 16x16 tiles.
// A-frag layout (16x16x32 bf16): row=lane&15, k=(lane>>4)*8+j
// B-frag layout:                 col=lane&15, k=(lane>>4)*8+j  (load from W^T)
// C/D layout:                    col=lane&15, row=(lane>>4)*4+reg
__global__ __launch_bounds__(256, 2) void hz_kernel(
    const unsigned short* __restrict__ meanb, const float* __restrict__ xg,
    const float* __restrict__ eps,
    const unsigned short* __restrict__ WlT, const unsigned short* __restrict__ WrT,
    const unsigned short* __restrict__ muT, const unsigned short* __restrict__ lvT,
    const float* __restrict__ bl, const float* __restrict__ mub,
    const float* __restrict__ lvb, float* __restrict__ z, int ntiles)
{
    __shared__ unsigned short h_s[16][136];   // +8 pad

    int tid = threadIdx.x;
    int wave = tid >> 6;
    int lane = tid & 63;
    int lr = lane & 15;
    int lg = lane >> 4;

    int cb0 = wave * 32;
    int cb1 = cb0 + 16;

    bf16x8 wl[2][4], wr[2][4], mu[2][4], lv[2][4];
    #pragma unroll
    for (int kc = 0; kc < 4; ++kc) {
        int koff = kc * 32 + lg * 8;
        wl[0][kc] = *(const bf16x8*)&WlT[(cb0 + lr) * D + koff];
        wl[1][kc] = *(const bf16x8*)&WlT[(cb1 + lr) * D + koff];
        wr[0][kc] = *(const bf16x8*)&WrT[(cb0 + lr) * D + koff];
        wr[1][kc] = *(const bf16x8*)&WrT[(cb1 + lr) * D + koff];
        mu[0][kc] = *(const bf16x8*)&muT[(cb0 + lr) * D + koff];
        mu[1][kc] = *(const bf16x8*)&muT[(cb1 + lr) * D + koff];
        lv[0][kc] = *(const bf16x8*)&lvT[(cb0 + lr) * D + koff];
        lv[1][kc] = *(const bf16x8*)&lvT[(cb1 + lr) * D + koff];
    }
    float bias0 = bl[cb0 + lr], bias1 = bl[cb1 + lr];
    float mb0 = mub[cb0 + lr], mb1 = mub[cb1 + lr];
    float lb0 = lvb[cb0 + lr], lb1 = lvb[cb1 + lr];

    for (int t = blockIdx.x; t < ntiles; t += gridDim.x) {
        int rowbase = t * 16;
        int arow = rowbase + lr;

        bf16x8 am[4], ax[4];
        #pragma unroll
        for (int kc = 0; kc < 4; ++kc) {
            int koff = kc * 32 + lg * 8;
            am[kc] = *(const bf16x8*)&meanb[arow * D + koff];
            const float* xp = &xg[arow * D + koff];
            float4 x0 = *(const float4*)xp;
            float4 x1 = *(const float4*)(xp + 4);
            bf16x8 v;
            v[0] = (short)f2bf(x0.x); v[1] = (short)f2bf(x0.y);
            v[2] = (short)f2bf(x0.z); v[3] = (short)f2bf(x0.w);
            v[4] = (short)f2bf(x1.x); v[5] = (short)f2bf(x1.y);
            v[6] = (short)f2bf(x1.z); v[7] = (short)f2bf(x1.w);
            ax[kc] = v;
        }

        f32x4 h0 = {bias0, bias0, bias0, bias0};
        f32x4 h1 = {bias1, bias1, bias1, bias1};
        #pragma unroll
        for (int kc = 0; kc < 4; ++kc) {
            h0 = __builtin_amdgcn_mfma_f32_16x16x32_bf16(am[kc], wl[0][kc], h0, 0, 0, 0);
            h1 = __builtin_amdgcn_mfma_f32_16x16x32_bf16(am[kc], wl[1][kc], h1, 0, 0, 0);
            h0 = __builtin_amdgcn_mfma_f32_16x16x32_bf16(ax[kc], wr[0][kc], h0, 0, 0, 0);
            h1 = __builtin_amdgcn_mfma_f32_16x16x32_bf16(ax[kc], wr[1][kc], h1, 0, 0, 0);
        }

        __syncthreads();   // prev iteration's z-phase LDS reads complete
        #pragma unroll
        for (int r = 0; r < 4; ++r) {
            int rit = lg * 4 + r;
            h_s[rit][cb0 + lr] = f2bf(h0[r]);
            h_s[rit][cb1 + lr] = f2bf(h1[r]);
        }
        __syncthreads();

        bf16x8 ah[4];
        #pragma unroll
        for (int kc = 0; kc < 4; ++kc) {
            int koff = kc * 32 + lg * 8;
            ah[kc] = *(const bf16x8*)&h_s[lr][koff];
        }
        f32x4 zm0 = {mb0, mb0, mb0, mb0}, zm1 = {mb1, mb1, mb1, mb1};
        f32x4 zl0 = {lb0, lb0, lb0, lb0}, zl1 = {lb1, lb1, lb1, lb1};
        #pragma unroll
        for (int kc = 0; kc < 4; ++kc) {
            zm0 = __builtin_amdgcn_mfma_f32_16x16x32_bf16(ah[kc], mu[0][kc], zm0, 0, 0, 0);
            zm1 = __builtin_amdgcn_mfma_f32_16x16x32_bf16(ah[kc], mu[1][kc], zm1, 0, 0, 0);
            zl0 = __builtin_amdgcn_mfma_f32_16x16x32_bf16(ah[kc], lv[0][kc], zl0, 0, 0, 0);
            zl1 = __builtin_amdgcn_mfma_f32_16x16x32_bf16(ah[kc], lv[1][kc], zl1, 0, 0, 0);
        }
        #pragma unroll
        for (int r = 0; r < 4; ++r) {
            int orow = rowbase + lg * 4 + r;
            float e0 = eps[orow * D + cb0 + lr];
            float e1 = eps[orow * D + cb1 + lr];
            z[orow * D + cb0 + lr] = zm0[r] + e0 * __expf(zl0[r]);
            z[orow * D + cb1 + lr] = zm1[r] + e1 * __expf(zl1[r]);
        }
    }
}

extern "C" void kernel_launch(void* const* d_in, const int* in_sizes, int n_in,
                              void* d_out, int out_size, void* d_ws, size_t ws_size,
                              hipStream_t stream)
{
    const float* xd  = (const float*)d_in[0];
    const float* xg  = (const float*)d_in[1];
    const int* esrc  = (const int*)d_in[2];
    const int* edst  = (const int*)d_in[3];
    const float* eps = (const float*)d_in[4];
    const float* Wl  = (const float*)d_in[5];
    const float* bl  = (const float*)d_in[6];
    const float* Wr  = (const float*)d_in[7];
    const float* muW = (const float*)d_in[8];
    const float* mub = (const float*)d_in[9];
    const float* lvW = (const float*)d_in[10];
    const float* lvb = (const float*)d_in[11];

    int E = in_sizes[2];
    int ndis = in_sizes[0] / D;      // 20000
    int ngene = in_sizes[1] / D;     // 100000
    int nchunks = (ngene + CHUNK - 1) / CHUNK;   // 98 (<=128)

    // ---- ws layout ----
    char* p = (char*)d_ws;
    int* deg      = (int*)p;  p += (size_t)ngene * 4;
    int* offs     = (int*)p;  p += (size_t)(ngene + 1) * 4;
    int* cursor   = (int*)p;  p += (size_t)ngene * 4;
    int* chunksum = (int*)p;  p += 128 * 4;
    p = (char*)(((size_t)p + 255) & ~(size_t)255);
    unsigned short* xdb   = (unsigned short*)p;  p += (size_t)ndis * D * 2;
    unsigned short* WlT   = (unsigned short*)p;  p += D * D * 2;
    unsigned short* WrT   = (unsigned short*)p;  p += D * D * 2;
    unsigned short* muT   = (unsigned short*)p;  p += D * D * 2;
    unsigned short* lvT   = (unsigned short*)p;  p += D * D * 2;
    unsigned short* meanb = (unsigned short*)p;  p += (size_t)ngene * D * 2;
    int* csr_src  = (int*)p;  // E ints

    hipMemsetAsync(deg, 0, (size_t)ngene * sizeof(int), stream);

    hist_kernel<<<2048, 256, 0, stream>>>(edst, deg, E);
    chunksum_kernel<<<nchunks, 256, 0, stream>>>(deg, chunksum, ngene);
    scanchunks_kernel<<<1, 128, 0, stream>>>(chunksum, offs, nchunks, ngene, E);
    offsets_kernel<<<nchunks, 256, 0, stream>>>(deg, chunksum, offs, cursor, ngene);

    // 256 slices x 8 partitions = 2048 blocks; blockIdx&7 selects dst-range partition
    fill_kernel<<<2048, 256, 0, stream>>>(esrc, edst, cursor, csr_src, E, ngene);

    int n8 = ndis * D / 8;
    cvt_xd_kernel<<<(n8 + 255) / 256, 256, 0, stream>>>(xd, xdb, n8);
    cvt_w_kernel<<<4, 256, 0, stream>>>(Wl, Wr, muW, lvW, WlT, WrT, muT, lvT);

    gather_kernel<<<(ngene + 15) / 16, 256, 0, stream>>>(offs, csr_src, xdb, meanb, ngene);

    int ntiles = (ngene + 15) / 16;   // 6250 (exact for 100000)
    hz_kernel<<<2048, 256, 0, stream>>>(meanb, xg, eps, WlT, WrT, muT, lvT,
                                        bl, mub, lvb, (float*)d_out, ntiles);
}